// Round 1
// baseline (532.467 us; speedup 1.0000x reference)
//
#include <hip/hip_runtime.h>

// Correlation layer: out[b,k,i,j] = (1/C) * sum_c f1[b,c,i,j] * f2[b,c,i+di,j+dj]
// k = (di+4)*9 + (dj+4), di,dj in [-4,4], f2 zero-padded.
// B=8, C=128, H=128, W=256 -> out (8,81,128,256) fp32.
//
// Design v1:
//  - block = 9 waves (64x9 threads); wave wy handles di = wy-4  -> acc[9 dj][8 px] = 72 VGPRs
//  - tile = TI=2 rows x W=256 cols; lanes 0..31 row i0, lanes 32..63 row i0+1; 8 px/thread
//  - f2 staged to LDS per channel-chunk (CC=4): 10 rows x 264 cols (+-4 col halo, zeros)
//    double-buffered; register-staged pipeline (global loads issued 2 chunks ahead)
//  - f1 read directly from global (L1 serves the 9x cross-wave reuse; keeps LDS pipe for f2)
//  - XCD swizzle: b = blk&7 -> each XCD owns one batch image -> i-halo reuse via its L2

#define BB 8
#define CC_TOT 128
#define HH 128
#define WW 256
#define NK 81
#define TI 2
#define CCH 4               // channels per chunk
#define NCHUNK (CC_TOT/CCH) // 32
#define ROWS (TI+8)         // 10
#define LROW 264            // cols -4..259
#define NUNIT (CCH*ROWS)    // 40 row-stages per chunk
#define LDSBUF (CCH*ROWS*LROW) // floats per buffer = 10560

__global__ __launch_bounds__(576, 3)
void corr_kernel(const float* __restrict__ f1, const float* __restrict__ f2,
                 float* __restrict__ out) {
    __shared__ __align__(16) float lds[2][CCH][ROWS][LROW]; // 84,480 B

    const int l    = threadIdx.x;      // 0..63
    const int wy   = threadIdx.y;      // 0..8  -> di = wy-4
    const int sl   = l & 31;
    const int half = l >> 5;           // which of the 2 tile rows
    const int blk  = blockIdx.x;
    const int b    = blk & 7;          // XCD affinity: batch per XCD
    const int it   = blk >> 3;         // 0..63
    const int i0   = it * TI;
    const int gi   = i0 + half;        // output row, always < 128
    const int j0   = sl * 8;           // 8 consecutive cols per thread

    // ---- zero all LDS once (halo cols + out-of-range rows stay zero) ----
    {
        float4* p = (float4*)&lds[0][0][0][0];
        const int tot = (int)(sizeof(lds) / 16);
        for (int idx = wy * 64 + l; idx < tot; idx += 576)
            p[idx] = make_float4(0.f, 0.f, 0.f, 0.f);
    }

    // ---- precompute this thread's staging units (wave-uniform) ----
    bool uval[5];
    const float* gb[5];
    float* lb[5];
    const size_t chunkstride = (size_t)CCH * HH * WW;
#pragma unroll
    for (int i = 0; i < 5; ++i) {
        uval[i] = false; gb[i] = f2; lb[i] = &lds[0][0][0][0];
        const int u = wy + 9 * i;
        if (u < NUNIT) {
            const int cc = u / ROWS, rl = u - cc * ROWS;
            const int R  = i0 - 4 + rl;
            if (R >= 0 && R < HH) {
                uval[i] = true;
                gb[i] = f2 + ((size_t)(b * CC_TOT + cc) * HH + R) * WW + l * 4;
                lb[i] = &lds[0][cc][rl][4 + l * 4];
            }
        }
    }

    float4 r[5];
    auto loadr = [&](int q) {
#pragma unroll
        for (int i = 0; i < 5; ++i)
            if (uval[i]) r[i] = *(const float4*)(gb[i] + (size_t)q * chunkstride);
    };
    auto storer = [&](int bsel) {
#pragma unroll
        for (int i = 0; i < 5; ++i)
            if (uval[i]) *(float4*)(lb[i] + bsel * LDSBUF) = r[i];
    };

    float acc[9][8];
#pragma unroll
    for (int a = 0; a < 9; ++a)
#pragma unroll
        for (int p = 0; p < 8; ++p) acc[a][p] = 0.f;

    const float* f1base = f1 + ((size_t)(b * CC_TOT) * HH + gi) * WW + j0;
    const size_t cstride = (size_t)HH * WW;

    auto compute = [&](int q, int bsel) {
#pragma unroll
        for (int cc = 0; cc < CCH; ++cc) {
            const int c = q * CCH + cc;
            const float* f1p = f1base + (size_t)c * cstride;
            float4 a0 = *(const float4*)f1p;
            float4 a1 = *(const float4*)(f1p + 4);
            const float* wp = &lds[bsel][cc][wy + half][8 * sl]; // j = j0-4 .. j0+11
            float4 w0 = *(const float4*)wp;
            float4 w1 = *(const float4*)(wp + 4);
            float4 w2 = *(const float4*)(wp + 8);
            float4 w3 = *(const float4*)(wp + 12);
            const float f1v[8] = {a0.x, a0.y, a0.z, a0.w, a1.x, a1.y, a1.z, a1.w};
            const float win[16] = {w0.x, w0.y, w0.z, w0.w, w1.x, w1.y, w1.z, w1.w,
                                   w2.x, w2.y, w2.z, w2.w, w3.x, w3.y, w3.z, w3.w};
#pragma unroll
            for (int dj = 0; dj < 9; ++dj)
#pragma unroll
                for (int p = 0; p < 8; ++p)
                    acc[dj][p] += f1v[p] * win[p + dj];
        }
    };

    // ---- pipeline: loads 2 chunks ahead, LDS double-buffered ----
    loadr(0);
    __syncthreads();          // zero-init visible
    storer(0);
    loadr(1);
    for (int q = 0; q < NCHUNK; ++q) {
        __syncthreads();      // chunk q staged; everyone done reading buf[(q+1)&1]
        if (q + 1 < NCHUNK) storer((q + 1) & 1);
        if (q + 2 < NCHUNK) loadr(q + 2);
        compute(q, q & 1);
    }

    // ---- epilogue: /C and store ----
    const float s = 1.0f / 128.0f;
#pragma unroll
    for (int dj = 0; dj < 9; ++dj) {
        const int k = wy * 9 + dj;
        float* op = out + ((size_t)(b * NK + k) * HH + gi) * WW + j0;
        *(float4*)op = make_float4(acc[dj][0] * s, acc[dj][1] * s,
                                   acc[dj][2] * s, acc[dj][3] * s);
        *(float4*)(op + 4) = make_float4(acc[dj][4] * s, acc[dj][5] * s,
                                         acc[dj][6] * s, acc[dj][7] * s);
    }
}

extern "C" void kernel_launch(void* const* d_in, const int* in_sizes, int n_in,
                              void* d_out, int out_size, void* d_ws, size_t ws_size,
                              hipStream_t stream) {
    const float* f1 = (const float*)d_in[0];
    const float* f2 = (const float*)d_in[1];
    float* out = (float*)d_out;
    dim3 grid(BB * (HH / TI));   // 512 blocks
    dim3 block(64, 9);           // 9 waves: one per di
    hipLaunchKernelGGL(corr_kernel, grid, block, 0, stream, f1, f2, out);
}

// Round 2
// 470.210 us; speedup vs baseline: 1.1324x; 1.1324x over previous
//
#include <hip/hip_runtime.h>

// Correlation: out[b,(di+4)*9+(dj+4),i,j] = (1/128) * sum_c f1[b,c,i,j]*f2[b,c,i+di,j+dj]
// B=8 C=128 H=128 W=256, di,dj in [-4,4], f2 zero-padded.
//
// v2: occupancy + conflict-free LDS.
//  - block = 9 waves (64x9); wave wy owns di=wy-4; tile = 1 row x 256 cols
//  - thread lane l owns 4 px (cols 4l..4l+3): acc[9 dj][4 px] = 36 VGPR
//  - window read = 3x ds_read_b128 at 16B lane stride -> conflict-free (8 lanes/cyc)
//  - LDS: 2 channels/chunk x 9 rows x 264 cols, double-buffered = 38,016 B
//    -> 2+ blocks/CU resident (vs 1 in v1) so barrier drains are covered
//  - f2 staging: wave wy stages LDS row wy (image row i0-4+wy) for both channels,
//    register-staged 2 chunks ahead; f1 prefetched 1 chunk ahead into regs
//  - XCD swizzle: b = blk&7 (batch per XCD) for f2 halo reuse in that XCD's L2

#define BB 8
#define CT 128
#define HH 128
#define WW 256
#define NK 81
#define CCH 2
#define NCHUNK (CT/CCH)        // 64
#define ROWS 9                 // i0-4 .. i0+4
#define LROW 264               // cols -4..259 (4-col zero halo each side)
#define LDSBUF (CCH*ROWS*LROW) // floats per buffer = 4752

__global__ __launch_bounds__(576, 6)
void corr_kernel(const float* __restrict__ f1, const float* __restrict__ f2,
                 float* __restrict__ out) {
    __shared__ __align__(16) float lds[2][CCH][ROWS][LROW]; // 38,016 B

    const int l   = threadIdx.x;   // 0..63
    const int wy  = threadIdx.y;   // 0..8 -> di = wy-4; also the LDS row it reads
    const int blk = blockIdx.x;
    const int b   = blk & 7;       // XCD affinity
    const int i0  = blk >> 3;      // output row 0..127

    // ---- zero LDS once (halo cols + out-of-image rows stay zero) ----
    {
        float4* p = (float4*)&lds[0][0][0][0];
        const int tot = (int)(sizeof(lds) / 16);
        for (int idx = wy * 64 + l; idx < tot; idx += 576)
            p[idx] = make_float4(0.f, 0.f, 0.f, 0.f);
    }

    // ---- f2 staging: wave wy stages image row R = i0-4+wy into LDS row wy ----
    const int  R      = i0 - 4 + wy;
    const bool rvalid = (R >= 0) && (R < HH);            // wave-uniform
    const size_t cstride = (size_t)HH * WW;
    float* lb0 = &lds[0][0][wy][4 + 4 * l];
    float* lb1 = &lds[0][1][wy][4 + 4 * l];

    float4 r0, r1;
    auto loadr = [&](int q) {
        if (rvalid) {
            const float* p = f2 + ((size_t)(b * CT + q * CCH) * HH + R) * WW + 4 * l;
            r0 = *(const float4*)p;
            r1 = *(const float4*)(p + cstride);
        }
    };
    auto storer = [&](int s) {
        if (rvalid) {
            *(float4*)(lb0 + s * LDSBUF) = r0;
            *(float4*)(lb1 + s * LDSBUF) = r1;
        }
    };

    // ---- f1: this thread's 4 px, prefetched one chunk ahead ----
    const float* f1base = f1 + ((size_t)(b * CT) * HH + i0) * WW + 4 * l;
    auto loadf1 = [&](int q, float4& a0, float4& a1) {
        const float* p = f1base + (size_t)(q * CCH) * cstride;
        a0 = *(const float4*)p;
        a1 = *(const float4*)(p + cstride);
    };

    float acc[9][4];
#pragma unroll
    for (int d = 0; d < 9; ++d)
#pragma unroll
        for (int p = 0; p < 4; ++p) acc[d][p] = 0.f;

    auto compute = [&](int s, const float4& a0, const float4& a1) {
#pragma unroll
        for (int cc = 0; cc < CCH; ++cc) {
            const float* wp = &lds[s][cc][wy][4 * l]; // image cols 4l-4 .. 4l+7
            float4 w0 = *(const float4*)wp;
            float4 w1 = *(const float4*)(wp + 4);
            float4 w2 = *(const float4*)(wp + 8);
            const float4& a = cc ? a1 : a0;
            const float fv[4]   = {a.x, a.y, a.z, a.w};
            const float win[12] = {w0.x, w0.y, w0.z, w0.w,
                                   w1.x, w1.y, w1.z, w1.w,
                                   w2.x, w2.y, w2.z, w2.w};
#pragma unroll
            for (int d = 0; d < 9; ++d)
#pragma unroll
                for (int p = 0; p < 4; ++p)
                    acc[d][p] += fv[p] * win[p + d];
        }
    };

    // ---- pipeline: f2 loads 2 ahead (via regs), LDS double-buffered, f1 1 ahead ----
    float4 a0, a1, n0, n1;
    loadr(0);
    loadf1(0, a0, a1);
    __syncthreads();          // zero-init visible
    storer(0);
    loadr(1);
    for (int q = 0; q < NCHUNK; ++q) {
        __syncthreads();      // chunk q staged; buffer (q+1)&1 free to overwrite
        if (q + 1 < NCHUNK) storer((q + 1) & 1);
        if (q + 2 < NCHUNK) loadr(q + 2);
        if (q + 1 < NCHUNK) loadf1(q + 1, n0, n1);
        compute(q & 1, a0, a1);
        a0 = n0; a1 = n1;
    }

    // ---- epilogue: /C and store (coalesced float4) ----
    const float s = 1.0f / 128.0f;
#pragma unroll
    for (int d = 0; d < 9; ++d) {
        const int k = wy * 9 + d;
        float* op = out + ((size_t)(b * NK + k) * HH + i0) * WW + 4 * l;
        *(float4*)op = make_float4(acc[d][0] * s, acc[d][1] * s,
                                   acc[d][2] * s, acc[d][3] * s);
    }
}

extern "C" void kernel_launch(void* const* d_in, const int* in_sizes, int n_in,
                              void* d_out, int out_size, void* d_ws, size_t ws_size,
                              hipStream_t stream) {
    const float* f1 = (const float*)d_in[0];
    const float* f2 = (const float*)d_in[1];
    float* out = (float*)d_out;
    dim3 grid(BB * HH);      // 1024 blocks
    dim3 block(64, 9);       // 9 waves: one per di
    hipLaunchKernelGGL(corr_kernel, grid, block, 0, stream, f1, f2, out);
}

// Round 3
// 419.294 us; speedup vs baseline: 1.2699x; 1.1214x over previous
//
#include <hip/hip_runtime.h>

// Correlation: out[b,(di+4)*9+(dj+4),i,j] = (1/128) * sum_c f1[b,c,i,j]*f2[b,c,i+di,j+dj]
// B=8 C=128 H=128 W=256, di,dj in [-4,4], f2 zero-padded.
//
// v3: BARRIER-FREE. Key insight from v2 post-mortem: wave wy only ever reads the
// LDS row it staged itself (lds[*][*][wy][*]) -> no cross-wave sharing -> all
// __syncthreads() were pure lockstep overhead (cost ~4x). Now each wave:
//  - zeros its own halo (or full row when out-of-image) privately
//  - runs its own double-buffered, 2-chunk-ahead global->reg->LDS pipeline
//  - ds_write -> ds_read ordering within the wave via compiler lgkmcnt waits
// Layout per wave: window read = 3x ds_read_b128 at 16B lane stride (conflict-free).
// 3 blocks/CU (LDS 38.4KB) = 27 waves/CU, all self-paced.

#define BB 8
#define CT 128
#define HH 128
#define WW 256
#define NK 81
#define CCH 2
#define NCHUNK (CT/CCH)        // 64
#define ROWS 9                 // i0-4 .. i0+4 (row index = wy, private per wave)
#define LROW 264               // cols -4..259 (4-col zero halo each side)
#define LDSBUF (CCH*ROWS*LROW) // floats per buffer = 4752

__global__ __launch_bounds__(576)
void corr_kernel(const float* __restrict__ f1, const float* __restrict__ f2,
                 float* __restrict__ out) {
    __shared__ __align__(16) float lds[2][CCH][ROWS][LROW]; // 38,016 B

    const int l   = threadIdx.x;   // 0..63
    const int wy  = threadIdx.y;   // 0..8 -> di = wy-4; private LDS row index
    const int blk = blockIdx.x;
    const int b   = blk & 7;       // XCD affinity: batch per XCD
    const int i0  = blk >> 3;      // output row 0..127

    const int  R      = i0 - 4 + wy;           // f2 image row this wave needs
    const bool rvalid = (R >= 0) && (R < HH);  // wave-uniform

    // ---- per-wave private zero-init (no barrier needed: only this wave reads) ----
    if (rvalid) {
        // zero just the 4-col halos: 2 buf x 2 ch x 8 cols = 32 floats
        if (l < 32) {
            const int buf = l >> 4, cc = (l >> 3) & 1, pos = l & 7;
            const int col = (pos < 4) ? pos : (256 + pos);
            lds[buf][cc][wy][col] = 0.f;
        }
    } else {
        // whole row must read as zero
#pragma unroll
        for (int t = 0; t < 4; ++t)
            for (int col = l; col < LROW; col += 64)
                lds[t >> 1][t & 1][wy][col] = 0.f;
    }

    // ---- f2 staging: this wave stages image row R into LDS row wy ----
    const size_t cstride = (size_t)HH * WW;
    float* lb0 = &lds[0][0][wy][4 + 4 * l];
    float* lb1 = &lds[0][1][wy][4 + 4 * l];

    float4 r0, r1;
    auto loadr = [&](int q) {
        if (rvalid) {
            const float* p = f2 + ((size_t)(b * CT + q * CCH) * HH + R) * WW + 4 * l;
            r0 = *(const float4*)p;
            r1 = *(const float4*)(p + cstride);
        }
    };
    auto storer = [&](int s) {
        if (rvalid) {
            *(float4*)(lb0 + s * LDSBUF) = r0;
            *(float4*)(lb1 + s * LDSBUF) = r1;
        }
    };

    // ---- f1: this thread's 4 px, prefetched one chunk ahead ----
    const float* f1base = f1 + ((size_t)(b * CT) * HH + i0) * WW + 4 * l;
    auto loadf1 = [&](int q, float4& a0, float4& a1) {
        const float* p = f1base + (size_t)(q * CCH) * cstride;
        a0 = *(const float4*)p;
        a1 = *(const float4*)(p + cstride);
    };

    float acc[9][4];
#pragma unroll
    for (int d = 0; d < 9; ++d)
#pragma unroll
        for (int p = 0; p < 4; ++p) acc[d][p] = 0.f;

    auto compute = [&](int s, const float4& a0, const float4& a1) {
#pragma unroll
        for (int cc = 0; cc < CCH; ++cc) {
            const float* wp = &lds[s][cc][wy][4 * l]; // image cols 4l-4 .. 4l+7
            float4 w0 = *(const float4*)wp;
            float4 w1 = *(const float4*)(wp + 4);
            float4 w2 = *(const float4*)(wp + 8);
            const float4& a = cc ? a1 : a0;
            const float fv[4]   = {a.x, a.y, a.z, a.w};
            const float win[12] = {w0.x, w0.y, w0.z, w0.w,
                                   w1.x, w1.y, w1.z, w1.w,
                                   w2.x, w2.y, w2.z, w2.w};
#pragma unroll
            for (int d = 0; d < 9; ++d)
#pragma unroll
                for (int p = 0; p < 4; ++p)
                    acc[d][p] += fv[p] * win[p + d];
        }
    };

    // ---- per-wave pipeline: f2 loads 2 ahead, LDS double-buffered, f1 1 ahead ----
    float4 a0, a1, n0, n1;
    loadr(0);
    loadf1(0, a0, a1);
    storer(0);            // same-wave ordering vs zero-init/reads via lgkmcnt
    loadr(1);
    for (int q = 0; q < NCHUNK; ++q) {
        if (q + 1 < NCHUNK) storer((q + 1) & 1);
        if (q + 2 < NCHUNK) loadr(q + 2);
        if (q + 1 < NCHUNK) loadf1(q + 1, n0, n1);
        compute(q & 1, a0, a1);
        a0 = n0; a1 = n1;
    }

    // ---- epilogue: /C and store (coalesced float4) ----
    const float s = 1.0f / 128.0f;
#pragma unroll
    for (int d = 0; d < 9; ++d) {
        const int k = wy * 9 + d;
        float* op = out + ((size_t)(b * NK + k) * HH + i0) * WW + 4 * l;
        *(float4*)op = make_float4(acc[d][0] * s, acc[d][1] * s,
                                   acc[d][2] * s, acc[d][3] * s);
    }
}

extern "C" void kernel_launch(void* const* d_in, const int* in_sizes, int n_in,
                              void* d_out, int out_size, void* d_ws, size_t ws_size,
                              hipStream_t stream) {
    const float* f1 = (const float*)d_in[0];
    const float* f2 = (const float*)d_in[1];
    float* out = (float*)d_out;
    dim3 grid(BB * HH);      // 1024 blocks
    dim3 block(64, 9);       // 9 waves: one per di, fully independent
    hipLaunchKernelGGL(corr_kernel, grid, block, 0, stream, f1, f2, out);
}